// Round 1
// baseline (238.139 us; speedup 1.0000x reference)
//
#include <hip/hip_runtime.h>

// DecayModel: out[b,i,h] = (fwd[i] + bwd[i]) / norm[i], decay = 0.5
//   fwd[i] = sum_{k<=i} 0.5^{i-k} x[k],  bwd[i] = sum_{k>=i} 0.5^{k-i} x[k]
//   norm[i] = 4 - 2^{-i} - 2^{-(S-1-i)}   (== 4.0f exactly for interior i)
//
// R6 -> R7: rolling-chunk scan to kill the 2.5x halo read amplification and
// the burst/idle load duty cycle of the tile-per-block design.
// Each block owns (b, h-half, s-chunk of C=128 rows) and walks it in W=16-row
// subtiles with a register triple buffer:
//   - fwd recurrence carried EXACTLY across subtiles (single K=12-tap left
//     halo prologue per chunk),
//   - bwd K=12 lookahead taken from the next subtile's buffer (already
//     loaded) -> only true halo re-read is 12 rows at the chunk's right edge,
//   - prefetch for subtile n+2 issues before compute of subtile n -> each
//     wave keeps a full 16KB load burst in flight through every compute
//     phase (4 waves/CU x 16KB >> 9.2KB latency-BW product per CU).
// Read amplification 2.5x -> 1.19x; predicted HBM traffic ~300MB total.
// All buffer indices are compile-time constants after full unroll (rule #20:
// runtime-indexed ext_vector arrays would go to scratch -- verify localMem=0).

constexpr int B = 16;
constexpr int S = 2048;
constexpr int H = 1024;
constexpr int HV = H / 4;        // 256 v4f per row
constexpr int C = 128;           // chunk rows per block
constexpr int W = 16;            // subtile rows (must be >= K)
constexpr int NT = C / W;        // 8 subtiles per chunk
constexpr int K = 12;            // halo taps: 0.5^13 * 6sigma ~ 7e-4 << tol
constexpr int THREADS = 128;     // 2 waves; each thread owns one v4f column
constexpr int NH = HV / THREADS; // 2 h-halves per row
constexpr int NCH = S / C;       // 16 chunks

typedef float v4f __attribute__((ext_vector_type(4)));

__global__ __launch_bounds__(THREADS, 1) void decay_kernel(
    const v4f* __restrict__ x, v4f* __restrict__ out) {
    const int chunk = blockIdx.x / NH;
    const int hsel = blockIdx.x % NH;
    const int b = blockIdx.y;
    const int s0 = chunk * C;

    const size_t colBase = (size_t)b * S * HV + (size_t)(hsel * THREADS) +
                           threadIdx.x;
    const v4f* __restrict__ xp = x + colBase;   // xp[s*HV] = x[b, s, col]
    v4f* __restrict__ op = out + colBase;

    v4f xb[3][W];  // rolling triple buffer; indices static after unroll
    v4f hv[K];     // left-halo rows (prologue only; regs reused after)

    // ---- prologue: issue halo + tile0 + tile1 loads in one burst ----
#pragma unroll
    for (int r = 0; r < K; ++r) {
        const int s = s0 - K + r;
        const int sc = s < 0 ? 0 : s;  // clamp; value ignored for chunk 0
        hv[r] = xp[(size_t)sc * HV];
    }
#pragma unroll
    for (int r = 0; r < W; ++r) xb[0][r] = xp[(size_t)(s0 + r) * HV];
#pragma unroll
    for (int r = 0; r < W; ++r) xb[1][r] = xp[(size_t)(s0 + W + r) * HV];

    // fwd carry-in from left halo (exact K-tap truncation; zero for chunk 0)
    v4f facc = (v4f)0.0f;
    if (chunk > 0) {
#pragma unroll
        for (int r = 0; r < K; ++r) facc = 0.5f * facc + hv[r];
    }

    const bool interior = (s0 >= 32) && (s0 + C <= S - 32);
    const bool lastChunk = (chunk == NCH - 1);

#pragma unroll
    for (int n = 0; n < NT; ++n) {
        // ---- prefetch subtile n+2 (subtile NT == right halo, K rows) ----
        if (n + 2 < NT) {
#pragma unroll
            for (int r = 0; r < W; ++r)
                xb[(n + 2) % 3][r] = xp[(size_t)(s0 + (n + 2) * W + r) * HV];
        } else if (n + 2 == NT) {
#pragma unroll
            for (int r = 0; r < K; ++r) {
                const int s = s0 + C + r;
                const int sc = s > S - 1 ? S - 1 : s;  // clamp; zeroed below
                xb[(n + 2) % 3][r] = xp[(size_t)sc * HV];
            }
        }

        // ---- forward recurrence over subtile n (in place: x -> fwd) ----
        const v4f fprev = facc;  // fwd of last row of previous subtile
#pragma unroll
        for (int r = 0; r < W; ++r) {
            facc = 0.5f * facc + xb[n % 3][r];
            xb[n % 3][r] = facc;  // buffer now holds fwd
        }

        // zero right-halo values past the end of the sequence (wave-uniform;
        // only the last chunk's last subtile ever takes this)
        if (n == NT - 1) {
            if (lastChunk) {
#pragma unroll
                for (int r = 0; r < K; ++r) xb[(n + 1) % 3][r] = (v4f)0.0f;
            }
        }

        // ---- backward recurrence + combine + store ----
        v4f bacc = (v4f)0.0f;
#pragma unroll
        for (int j = K - 1; j >= 0; --j)  // K lookahead rows from subtile n+1
            bacc = 0.5f * bacc + xb[(n + 1) % 3][j];
#pragma unroll
        for (int r = W - 1; r >= 0; --r) {
            const v4f f = xb[n % 3][r];                       // fwd[i]
            const v4f fm1 = (r > 0) ? xb[n % 3][r - 1] : fprev;
            const v4f xt = f - 0.5f * fm1;                    // recover x[i]
            bacc = 0.5f * bacc + xt;                          // bwd[i]
            const int i = s0 + n * W + r;
            float rn = 0.25f;  // norm == 4 exactly for interior rows
            if (!interior) {
                rn = 1.0f / (4.0f - exp2f((float)(-i)) -
                             exp2f((float)(i - (S - 1))));
            }
            __builtin_nontemporal_store((f + bacc) * rn, &op[(size_t)i * HV]);
        }
    }
}

extern "C" void kernel_launch(void* const* d_in, const int* in_sizes, int n_in,
                              void* d_out, int out_size, void* d_ws,
                              size_t ws_size, hipStream_t stream) {
    const v4f* x = (const v4f*)d_in[0];
    v4f* out = (v4f*)d_out;
    dim3 grid(NCH * NH, B);  // 32 x 16 = 512 blocks, 2 per CU
    decay_kernel<<<grid, THREADS, 0, stream>>>(x, out);
}